// Round 4
// baseline (145.673 us; speedup 1.0000x reference)
//
#include <hip/hip_runtime.h>
#include <hip/hip_bf16.h>

// NCE / NT-Xent loss, B=4096, D=256, temp=0.5.
// loss = mean_i( log(sum_{j!=i} exp(sim_ij)) - sim_{i,(i+B)%N} ), N=8192.
// |sim| <= 1/temp = 2 => exp(sim) <= e^2: no online max needed, plain sum(exp).

constexpr int kN  = 8192;        // 2B rows
constexpr int kD  = 256;         // embedding dim
constexpr int kBH = 4096;        // B
constexpr int kChunks  = 32;     // column split for k_simlse (occupancy lever)
constexpr int kColsPer = kN / kChunks;            // 256
constexpr float kInvTemp = 2.0f;                  // 1/temp
constexpr float kInvTempLog2e = 2.8853900817779268f; // (1/temp)*log2(e)

typedef __attribute__((ext_vector_type(8))) short bf16x8;  // 8 bf16 = 4 VGPRs
typedef __attribute__((ext_vector_type(4))) float f32x4;

__device__ __forceinline__ unsigned short f2bf(float f) {
  union { float f; unsigned u; } x;
  x.f = f;
  unsigned u = x.u;
  return (unsigned short)((u + 0x7FFFu + ((u >> 16) & 1u)) >> 16);
}

// ---------------- kernel 1: row-normalize fp32 -> bf16, + zero accumulators
// One wave per row; lane loads float4 (16B), shfl-reduce sum of squares.
// Blocks 0..15 additionally zero the 16K-float accumulator region (s_sum,
// pos_sum) so k_simlse can atomicAdd into it (stream order guarantees
// completion before k_simlse starts).
__global__ void k_normalize(const float* __restrict__ e1,
                            const float* __restrict__ e2,
                            unsigned short* __restrict__ zn,
                            float* __restrict__ accum /* 2*kN floats */) {
  if (blockIdx.x < 16) {
    float4 z4 = {0.f, 0.f, 0.f, 0.f};
    *reinterpret_cast<float4*>(accum + blockIdx.x * 1024 + threadIdx.x * 4) = z4;
  }
  const int wave = threadIdx.x >> 6;
  const int lane = threadIdx.x & 63;
  const int row  = blockIdx.x * 4 + wave;
  const float* src = (row < kBH) ? (e1 + (size_t)row * kD)
                                 : (e2 + (size_t)(row - kBH) * kD);
  float4 v = *reinterpret_cast<const float4*>(src + lane * 4);
  float ssq = v.x * v.x + v.y * v.y + v.z * v.z + v.w * v.w;
#pragma unroll
  for (int m = 1; m < 64; m <<= 1) ssq += __shfl_xor(ssq, m);
  // norms ~16 for N(0,1) data; eps=1e-8 on the *product* can never bind.
  const float inv = 1.0f / sqrtf(ssq);
  ushort4 o;
  o.x = f2bf(v.x * inv);
  o.y = f2bf(v.y * inv);
  o.z = f2bf(v.z * inv);
  o.w = f2bf(v.w * inv);
  *reinterpret_cast<ushort4*>(zn + (size_t)row * kD + lane * 4) = o;
}

// ---------------- kernel 2: fused Z.Z^T + per-row sum(exp) ----------------
// Grid: 64 row-tiles (128 rows) x 32 col-chunks (256 cols) = 2048 blocks.
// ch = bid&31 so each XCD's round-robin share covers only 4 chunks (512KB of
// B -> per-XCD-L2 resident). Block: 4 waves; wave owns 32 rows as two 16-row
// MFMA subtiles, A in registers, B streamed from global (L2).
__global__ __launch_bounds__(256, 4)
void k_simlse(const unsigned short* __restrict__ zn,
              float* __restrict__ s_sum,
              float* __restrict__ pos_sum) {
  const int bid = blockIdx.x;
  const int rt  = bid >> 5;   // row tile 0..63
  const int ch  = bid & 31;   // column chunk 0..31
  const int wave = threadIdx.x >> 6;
  const int lane = threadIdx.x & 63;
  const int l15 = lane & 15;
  const int lhi = lane >> 4;
  const int rowBase = rt * 128 + wave * 32;
  const int colBase = ch * kColsPer;

  // A fragments: lane holds Z[row16 + (lane&15)][(lane>>4)*8 + ks*32 .. +7]
  bf16x8 a[2][8];
#pragma unroll
  for (int s = 0; s < 2; ++s) {
    const unsigned short* ap =
        zn + (size_t)(rowBase + s * 16 + l15) * kD + lhi * 8;
#pragma unroll
    for (int ks = 0; ks < 8; ++ks)
      a[s][ks] = *reinterpret_cast<const bf16x8*>(ap + ks * 32);
  }

  float sacc[2][4] = {{0.f, 0.f, 0.f, 0.f}, {0.f, 0.f, 0.f, 0.f}};
  float pacc[2][4] = {{0.f, 0.f, 0.f, 0.f}, {0.f, 0.f, 0.f, 0.f}};

  for (int ct = 0; ct < kColsPer / 16; ++ct) {
    const int cb = colBase + ct * 16;
    const unsigned short* bp = zn + (size_t)(cb + l15) * kD + lhi * 8;
    bf16x8 b[8];
#pragma unroll
    for (int ks = 0; ks < 8; ++ks)
      b[ks] = *reinterpret_cast<const bf16x8*>(bp + ks * 32);

    f32x4 acc0 = {0.f, 0.f, 0.f, 0.f};
    f32x4 acc1 = {0.f, 0.f, 0.f, 0.f};
#pragma unroll
    for (int ks = 0; ks < 8; ++ks) {
      acc0 = __builtin_amdgcn_mfma_f32_16x16x32_bf16(a[0][ks], b[ks], acc0, 0, 0, 0);
      acc1 = __builtin_amdgcn_mfma_f32_16x16x32_bf16(a[1][ks], b[ks], acc1, 0, 0, 0);
    }

    const int c = cb + l15;  // this lane's column (C/D layout: col = lane&15)
#pragma unroll
    for (int s = 0; s < 2; ++s) {
      const f32x4 acc = s ? acc1 : acc0;
      const int rbase16 = rowBase + s * 16;
      const bool diagT = (cb == rbase16);                       // wave-uniform
      const bool posT  = (cb == ((rbase16 + kBH) & (kN - 1)));  // wave-uniform
      if (!diagT && !posT) {
#pragma unroll
        for (int j = 0; j < 4; ++j)
          sacc[s][j] += exp2f(acc[j] * kInvTempLog2e);
      } else {
#pragma unroll
        for (int j = 0; j < 4; ++j) {
          const int row = rbase16 + lhi * 4 + j;  // C/D: row=(lane>>4)*4+j
          const float v = acc[j] * kInvTemp;
          float p = exp2f(acc[j] * kInvTempLog2e);
          if (diagT && c == row) p = 0.0f;                       // mask diagonal
          if (posT && c == ((row + kBH) & (kN - 1))) pacc[s][j] += v;
          sacc[s][j] += p;
        }
      }
    }
  }

  // Reduce across the 16-lane column group; lanes with (lane&15)==0 hold
  // rows rbase16 + lhi*4 + j and atomically fold into the per-row sums.
#pragma unroll
  for (int s = 0; s < 2; ++s) {
    const int rbase16 = rowBase + s * 16;
    const int pc = (rbase16 + kBH) & (kN - 1);
    const bool hasPos = (pc >= colBase) && (pc < colBase + kColsPer);
#pragma unroll
    for (int j = 0; j < 4; ++j) {
      float sv = sacc[s][j];
      float pv = pacc[s][j];
#pragma unroll
      for (int m = 1; m < 16; m <<= 1) {
        sv += __shfl_xor(sv, m);
        pv += __shfl_xor(pv, m);
      }
      if (l15 == 0) {
        const int row = rbase16 + lhi * 4 + j;
        atomicAdd(&s_sum[row], sv);
        if (hasPos) atomicAdd(&pos_sum[row], pv);
      }
    }
  }
}

// ---------------- kernel 3: log, subtract pos, final reduce ---------------
__global__ void k_final(const float* __restrict__ s_sum,
                        const float* __restrict__ pos_sum,
                        float* __restrict__ out) {
  __shared__ float red[16];
  float acc = 0.0f;
  for (int r = threadIdx.x; r < kN; r += 1024)
    acc += logf(s_sum[r]) - pos_sum[r];
#pragma unroll
  for (int m = 1; m < 64; m <<= 1) acc += __shfl_xor(acc, m);
  const int wave = threadIdx.x >> 6;
  const int lane = threadIdx.x & 63;
  if (lane == 0) red[wave] = acc;
  __syncthreads();
  if (threadIdx.x == 0) {
    float t = 0.0f;
#pragma unroll
    for (int w = 0; w < 16; ++w) t += red[w];
    out[0] = t / (float)kN;
  }
}

extern "C" void kernel_launch(void* const* d_in, const int* in_sizes, int n_in,
                              void* d_out, int out_size, void* d_ws, size_t ws_size,
                              hipStream_t stream) {
  const float* e1 = (const float*)d_in[0];
  const float* e2 = (const float*)d_in[1];
  float* out = (float*)d_out;

  // ws layout: [Zn bf16: N*D*2 = 4MB][s_sum: N*4][pos_sum: N*4]  ~4.07MB
  unsigned short* zn = (unsigned short*)d_ws;
  float* s_sum   = (float*)((char*)d_ws + (size_t)kN * kD * 2);
  float* pos_sum = s_sum + kN;

  hipLaunchKernelGGL(k_normalize, dim3(kN / 4), dim3(256), 0, stream,
                     e1, e2, zn, s_sum);
  hipLaunchKernelGGL(k_simlse, dim3(64 * kChunks), dim3(256), 0, stream,
                     zn, s_sum, pos_sum);
  hipLaunchKernelGGL(k_final, dim3(1), dim3(1024), 0, stream,
                     s_sum, pos_sum, out);
}

// Round 5
// 65.833 us; speedup vs baseline: 2.2128x; 2.2128x over previous
//
#include <hip/hip_runtime.h>
#include <hip/hip_bf16.h>

// NCE / NT-Xent loss, B=4096, D=256, temp=0.5.
// loss = mean_i( log(sum_{j!=i} exp(sim_ij)) - sim_{i,(i+B)%N} ), N=8192.
// |sim| <= 1/temp = 2 => exp(sim) <= e^2: no online max needed, plain sum(exp).
//
// R5 key change: Zn is stored in MFMA *fragment-tiled* layout so every load
// in the hot loop is a wave-contiguous 1KB transaction (fixes the TA/L1
// transaction bottleneck diagnosed in R4: strided 64B-segment loads).
//
// Tiled layout: for 16-row group g, element (row g*16+rr, dim d) with
// ks=d>>5, lhi=(d>>3)&3, dlo=d&7 lives at
//   zn[g*4096 + ks*512 + lhi*128 + rr*8 + dlo]
// so lane l's fragment ks of group g is the contiguous 16B at
//   zn + g*4096 + ks*512 + l*8      (l&15 = row-in-group, l>>4 = lhi). ✓MFMA

constexpr int kN  = 8192;        // 2B rows
constexpr int kD  = 256;         // embedding dim
constexpr int kBH = 4096;        // B
constexpr int kChunks  = 32;     // column split for k_simlse
constexpr int kColsPer = kN / kChunks;            // 256
constexpr float kInvTemp = 2.0f;                  // 1/temp
constexpr float kInvTempLog2e = 2.8853900817779268f; // (1/temp)*log2(e)

typedef __attribute__((ext_vector_type(8))) short bf16x8;  // 8 bf16 = 4 VGPRs
typedef __attribute__((ext_vector_type(4))) float f32x4;

__device__ __forceinline__ unsigned short f2bf(float f) {
  union { float f; unsigned u; } x;
  x.f = f;
  unsigned u = x.u;
  return (unsigned short)((u + 0x7FFFu + ((u >> 16) & 1u)) >> 16);
}

// ---------------- kernel 1: row-normalize fp32 -> bf16 (tiled layout) -----
// One wave per row; lane loads float4 (16B), shfl-reduce sum of squares.
// Blocks 0..15 additionally zero the accumulator region (s_sum, pos_sum);
// stream order guarantees completion before k_simlse's atomicAdds.
__global__ void k_normalize(const float* __restrict__ e1,
                            const float* __restrict__ e2,
                            unsigned short* __restrict__ zn,
                            float* __restrict__ accum /* 2*kN floats */) {
  if (blockIdx.x < 16) {
    float4 z4 = {0.f, 0.f, 0.f, 0.f};
    *reinterpret_cast<float4*>(accum + blockIdx.x * 1024 + threadIdx.x * 4) = z4;
  }
  const int wave = threadIdx.x >> 6;
  const int lane = threadIdx.x & 63;
  const int row  = blockIdx.x * 4 + wave;
  const float* src = (row < kBH) ? (e1 + (size_t)row * kD)
                                 : (e2 + (size_t)(row - kBH) * kD);
  float4 v = *reinterpret_cast<const float4*>(src + lane * 4);
  float ssq = v.x * v.x + v.y * v.y + v.z * v.z + v.w * v.w;
#pragma unroll
  for (int m = 1; m < 64; m <<= 1) ssq += __shfl_xor(ssq, m);
  // norms ~16 for N(0,1) data; eps=1e-8 on the *product* can never bind.
  const float inv = 1.0f / sqrtf(ssq);
  ushort4 o;
  o.x = f2bf(v.x * inv);
  o.y = f2bf(v.y * inv);
  o.z = f2bf(v.z * inv);
  o.w = f2bf(v.w * inv);
  // lane holds dims 4*lane .. 4*lane+3  ->  ks=lane>>3, lhi=(lane>>1)&3,
  // dlo=(lane&1)*4; write 8B into the tiled layout.
  const int g  = row >> 4;
  const int rr = row & 15;
  const size_t dst = (size_t)g * 4096 + (lane >> 3) * 512 +
                     ((lane >> 1) & 3) * 128 + rr * 8 + (lane & 1) * 4;
  *reinterpret_cast<ushort4*>(zn + dst) = o;
}

// ---------------- kernel 2: fused Z.Z^T + per-row sum(exp) ----------------
// Grid: 64 row-tiles (128 rows) x 32 col-chunks (256 cols) = 2048 blocks.
// Block: 4 waves; wave owns 32 rows as two 16-row MFMA subtiles, A in
// registers, B streamed from global (all loads wave-contiguous 1KB; the 4
// waves of a block read identical B addresses -> L1 hits).
__global__ __launch_bounds__(256, 4)
void k_simlse(const unsigned short* __restrict__ zn,
              float* __restrict__ s_sum,
              float* __restrict__ pos_sum) {
  const int bid = blockIdx.x;
  const int rt  = bid >> 5;   // row tile 0..63
  const int ch  = bid & 31;   // column chunk 0..31
  const int wave = threadIdx.x >> 6;
  const int lane = threadIdx.x & 63;
  const int l15 = lane & 15;
  const int lhi = lane >> 4;
  const int rowBase = rt * 128 + wave * 32;
  const int colBase = ch * kColsPer;

  // A fragments from tiled layout: group (rowBase/16 + s), contiguous loads.
  bf16x8 a[2][8];
#pragma unroll
  for (int s = 0; s < 2; ++s) {
    const unsigned short* ap =
        zn + (size_t)((rowBase >> 4) + s) * 4096 + lane * 8;
#pragma unroll
    for (int ks = 0; ks < 8; ++ks)
      a[s][ks] = *reinterpret_cast<const bf16x8*>(ap + ks * 512);
  }

  float sacc[2][4] = {{0.f, 0.f, 0.f, 0.f}, {0.f, 0.f, 0.f, 0.f}};
  float pacc[2][4] = {{0.f, 0.f, 0.f, 0.f}, {0.f, 0.f, 0.f, 0.f}};

  for (int ct = 0; ct < kColsPer / 16; ++ct) {
    const int cb = colBase + ct * 16;
    const unsigned short* bp = zn + (size_t)(cb >> 4) * 4096 + lane * 8;
    bf16x8 b[8];
#pragma unroll
    for (int ks = 0; ks < 8; ++ks)
      b[ks] = *reinterpret_cast<const bf16x8*>(bp + ks * 512);

    f32x4 acc0 = {0.f, 0.f, 0.f, 0.f};
    f32x4 acc1 = {0.f, 0.f, 0.f, 0.f};
#pragma unroll
    for (int ks = 0; ks < 8; ++ks) {
      acc0 = __builtin_amdgcn_mfma_f32_16x16x32_bf16(a[0][ks], b[ks], acc0, 0, 0, 0);
      acc1 = __builtin_amdgcn_mfma_f32_16x16x32_bf16(a[1][ks], b[ks], acc1, 0, 0, 0);
    }

    const int c = cb + l15;  // this lane's column (C/D layout: col = lane&15)
#pragma unroll
    for (int s = 0; s < 2; ++s) {
      const f32x4 acc = s ? acc1 : acc0;
      const int rbase16 = rowBase + s * 16;
      const bool diagT = (cb == rbase16);                       // wave-uniform
      const bool posT  = (cb == ((rbase16 + kBH) & (kN - 1)));  // wave-uniform
      if (!diagT && !posT) {
#pragma unroll
        for (int j = 0; j < 4; ++j)
          sacc[s][j] += exp2f(acc[j] * kInvTempLog2e);
      } else {
#pragma unroll
        for (int j = 0; j < 4; ++j) {
          const int row = rbase16 + lhi * 4 + j;  // C/D: row=(lane>>4)*4+j
          const float v = acc[j] * kInvTemp;
          float p = exp2f(acc[j] * kInvTempLog2e);
          if (diagT && c == row) p = 0.0f;                       // mask diagonal
          if (posT && c == ((row + kBH) & (kN - 1))) pacc[s][j] += v;
          sacc[s][j] += p;
        }
      }
    }
  }

  // Reduce across the 16-lane column group; lanes with (lane&15)==0 hold
  // rows rbase16 + lhi*4 + j and atomically fold into the per-row sums.
#pragma unroll
  for (int s = 0; s < 2; ++s) {
    const int rbase16 = rowBase + s * 16;
    const int pc = (rbase16 + kBH) & (kN - 1);
    const bool hasPos = (pc >= colBase) && (pc < colBase + kColsPer);
#pragma unroll
    for (int j = 0; j < 4; ++j) {
      float sv = sacc[s][j];
      float pv = pacc[s][j];
#pragma unroll
      for (int m = 1; m < 16; m <<= 1) {
        sv += __shfl_xor(sv, m);
        pv += __shfl_xor(pv, m);
      }
      if (l15 == 0) {
        const int row = rbase16 + lhi * 4 + j;
        atomicAdd(&s_sum[row], sv);
        if (hasPos) atomicAdd(&pos_sum[row], pv);
      }
    }
  }
}

// ---------------- kernel 3: log, subtract pos, final reduce ---------------
__global__ void k_final(const float* __restrict__ s_sum,
                        const float* __restrict__ pos_sum,
                        float* __restrict__ out) {
  __shared__ float red[16];
  float acc = 0.0f;
  for (int r = threadIdx.x; r < kN; r += 1024)
    acc += logf(s_sum[r]) - pos_sum[r];
#pragma unroll
  for (int m = 1; m < 64; m <<= 1) acc += __shfl_xor(acc, m);
  const int wave = threadIdx.x >> 6;
  const int lane = threadIdx.x & 63;
  if (lane == 0) red[wave] = acc;
  __syncthreads();
  if (threadIdx.x == 0) {
    float t = 0.0f;
#pragma unroll
    for (int w = 0; w < 16; ++w) t += red[w];
    out[0] = t / (float)kN;
  }
}

extern "C" void kernel_launch(void* const* d_in, const int* in_sizes, int n_in,
                              void* d_out, int out_size, void* d_ws, size_t ws_size,
                              hipStream_t stream) {
  const float* e1 = (const float*)d_in[0];
  const float* e2 = (const float*)d_in[1];
  float* out = (float*)d_out;

  // ws layout: [Zn bf16 tiled: N*D*2 = 4MB][s_sum: N*4][pos_sum: N*4] ~4.07MB
  unsigned short* zn = (unsigned short*)d_ws;
  float* s_sum   = (float*)((char*)d_ws + (size_t)kN * kD * 2);
  float* pos_sum = s_sum + kN;

  hipLaunchKernelGGL(k_normalize, dim3(kN / 4), dim3(256), 0, stream,
                     e1, e2, zn, s_sum);
  hipLaunchKernelGGL(k_simlse, dim3(64 * kChunks), dim3(256), 0, stream,
                     zn, s_sum, pos_sum);
  hipLaunchKernelGGL(k_final, dim3(1), dim3(1024), 0, stream,
                     s_sum, pos_sum, out);
}

// Round 7
// 62.817 us; speedup vs baseline: 2.3190x; 1.0480x over previous
//
#include <hip/hip_runtime.h>
#include <hip/hip_bf16.h>

// NCE / NT-Xent loss, B=4096, D=256, temp=0.5.
// loss = mean_i( log(sum_{j!=i} exp(sim_ij)) - sim_{i,(i+B)%N} ), N=8192.
// |sim| <= 1/temp = 2 => exp(sim) <= e^2: no online max needed, plain sum(exp).
//
// Zn is stored scaled by sqrt(2*log2(e)) = 1.6986436 so the MFMA output is
// directly the exp2 argument: acc = sim * (1/temp)*log2(e). pos = acc * ln2.
//
// Fragment-tiled Zn layout (R5): for 16-row group g, element (g*16+rr, d)
// with ks=d>>5, lhi=(d>>3)&3, dlo=d&7 lives at
//   zn[g*4096 + ks*512 + lhi*128 + rr*8 + dlo]
// so lane l's fragment ks of group g is the contiguous 16B at
//   zn + g*4096 + ks*512 + l*8   (wave-contiguous 1KB per fragment load).
//
// R6: __launch_bounds__(256,3) so A fragments (64 VGPR) stay register-
// resident (R5's VGPR=64 proved A was being re-loaded in-loop under the
// 128 cap), plus register double-buffered B with loads issued one tile
// ahead of the consuming MFMAs.

constexpr int kN  = 8192;        // 2B rows
constexpr int kD  = 256;         // embedding dim
constexpr int kBH = 4096;        // B
constexpr int kChunks  = 32;     // column split for k_simlse
constexpr int kColsPer = kN / kChunks;            // 256
constexpr float kSqrtScale = 1.6986436f;          // sqrt(2*log2(e))
constexpr float kLn2 = 0.6931471805599453f;       // acc -> sim/temp factor

typedef __attribute__((ext_vector_type(8))) short bf16x8;  // 8 bf16 = 4 VGPRs
typedef __attribute__((ext_vector_type(4))) float f32x4;

__device__ __forceinline__ unsigned short f2bf(float f) {
  union { float f; unsigned u; } x;
  x.f = f;
  unsigned u = x.u;
  return (unsigned short)((u + 0x7FFFu + ((u >> 16) & 1u)) >> 16);
}

// ---------------- kernel 1: row-normalize fp32 -> bf16 (tiled + scaled) ---
// One wave per row; lane loads float4 (16B), shfl-reduce sum of squares.
// Blocks 0..15 additionally zero the accumulator region (s_sum, pos_sum);
// stream order guarantees completion before k_simlse's atomicAdds.
__global__ void k_normalize(const float* __restrict__ e1,
                            const float* __restrict__ e2,
                            unsigned short* __restrict__ zn,
                            float* __restrict__ accum /* 2*kN floats */) {
  if (blockIdx.x < 16) {
    float4 z4 = {0.f, 0.f, 0.f, 0.f};
    *reinterpret_cast<float4*>(accum + blockIdx.x * 1024 + threadIdx.x * 4) = z4;
  }
  const int wave = threadIdx.x >> 6;
  const int lane = threadIdx.x & 63;
  const int row  = blockIdx.x * 4 + wave;
  const float* src = (row < kBH) ? (e1 + (size_t)row * kD)
                                 : (e2 + (size_t)(row - kBH) * kD);
  float4 v = *reinterpret_cast<const float4*>(src + lane * 4);
  float ssq = v.x * v.x + v.y * v.y + v.z * v.z + v.w * v.w;
#pragma unroll
  for (int m = 1; m < 64; m <<= 1) ssq += __shfl_xor(ssq, m);
  // norms ~16 for N(0,1) data; eps=1e-8 on the *product* can never bind.
  const float invs = kSqrtScale / sqrtf(ssq);
  ushort4 o;
  o.x = f2bf(v.x * invs);
  o.y = f2bf(v.y * invs);
  o.z = f2bf(v.z * invs);
  o.w = f2bf(v.w * invs);
  // lane holds dims 4*lane .. 4*lane+3  ->  ks=lane>>3, lhi=(lane>>1)&3,
  // dlo=(lane&1)*4; write 8B into the tiled layout.
  const int g  = row >> 4;
  const int rr = row & 15;
  const size_t dst = (size_t)g * 4096 + (lane >> 3) * 512 +
                     ((lane >> 1) & 3) * 128 + rr * 8 + (lane & 1) * 4;
  *reinterpret_cast<ushort4*>(zn + dst) = o;
}

// ---------------- kernel 2: fused Z.Z^T + per-row sum(exp) ----------------
// Grid: 64 row-tiles (128 rows) x 32 col-chunks (256 cols) = 2048 blocks.
// Block: 4 waves; wave owns 32 rows as two 16-row MFMA subtiles, A resident
// in registers, B register-double-buffered one tile ahead.
__global__ __launch_bounds__(256, 3)
void k_simlse(const unsigned short* __restrict__ zn,
              float* __restrict__ s_sum,
              float* __restrict__ pos_sum) {
  const int bid = blockIdx.x;
  const int rt  = bid >> 5;   // row tile 0..63
  const int ch  = bid & 31;   // column chunk 0..31
  const int wave = threadIdx.x >> 6;
  const int lane = threadIdx.x & 63;
  const int l15 = lane & 15;
  const int lhi = lane >> 4;
  const int rowBase = rt * 128 + wave * 32;
  const int colBase = ch * kColsPer;

  // A fragments from tiled layout: groups (rowBase/16) and +1, contiguous.
  bf16x8 a0[8], a1[8];
  {
    const unsigned short* ap0 = zn + (size_t)(rowBase >> 4) * 4096 + lane * 8;
#pragma unroll
    for (int ks = 0; ks < 8; ++ks) {
      a0[ks] = *reinterpret_cast<const bf16x8*>(ap0 + ks * 512);
      a1[ks] = *reinterpret_cast<const bf16x8*>(ap0 + 4096 + ks * 512);
    }
  }

  float sacc[2][4] = {{0.f, 0.f, 0.f, 0.f}, {0.f, 0.f, 0.f, 0.f}};
  float pacc[2][4] = {{0.f, 0.f, 0.f, 0.f}, {0.f, 0.f, 0.f, 0.f}};

  bf16x8 bA[8], bB[8];

  auto loadB = [&](bf16x8* b, int cb) {
    const unsigned short* bp =
        zn + (size_t)((cb & (kN - 1)) >> 4) * 4096 + lane * 8;
#pragma unroll
    for (int ks = 0; ks < 8; ++ks)
      b[ks] = *reinterpret_cast<const bf16x8*>(bp + ks * 512);
  };

  auto computeT = [&](const bf16x8* b, int cb) {
    f32x4 acc0 = {0.f, 0.f, 0.f, 0.f};
    f32x4 acc1 = {0.f, 0.f, 0.f, 0.f};
#pragma unroll
    for (int ks = 0; ks < 8; ++ks) {
      acc0 = __builtin_amdgcn_mfma_f32_16x16x32_bf16(a0[ks], b[ks], acc0, 0, 0, 0);
      acc1 = __builtin_amdgcn_mfma_f32_16x16x32_bf16(a1[ks], b[ks], acc1, 0, 0, 0);
    }
    const int c = cb + l15;  // this lane's column (C/D layout: col = lane&15)
#pragma unroll
    for (int s = 0; s < 2; ++s) {
      const f32x4 acc = s ? acc1 : acc0;
      const int rbase16 = rowBase + s * 16;
      const bool diagT = (cb == rbase16);                       // wave-uniform
      const bool posT  = (cb == ((rbase16 + kBH) & (kN - 1)));  // wave-uniform
      if (!diagT && !posT) {
#pragma unroll
        for (int j = 0; j < 4; ++j)
          sacc[s][j] += exp2f(acc[j]);        // acc is already sim/temp*log2e
      } else {
#pragma unroll
        for (int j = 0; j < 4; ++j) {
          const int row = rbase16 + lhi * 4 + j;  // C/D: row=(lane>>4)*4+j
          const float v = acc[j] * kLn2;          // sim/temp
          float p = exp2f(acc[j]);
          if (diagT && c == row) p = 0.0f;                       // mask diag
          if (posT && c == ((row + kBH) & (kN - 1))) pacc[s][j] += v;
          sacc[s][j] += p;
        }
      }
    }
  };

  // Software pipeline: loads for tile t+1 issue before MFMAs of tile t.
  int cb = colBase;
  loadB(bA, cb);
#pragma unroll 1
  for (int it = 0; it < kColsPer / 32; ++it) {
    loadB(bB, cb + 16);
    computeT(bA, cb);
    loadB(bA, cb + 32);   // final prefetch wraps (dead; compiler may DCE)
    computeT(bB, cb + 16);
    cb += 32;
  }

  // Reduce across the 16-lane column group; lanes with (lane&15)==0 hold
  // rows rbase16 + lhi*4 + j and atomically fold into the per-row sums.
#pragma unroll
  for (int s = 0; s < 2; ++s) {
    const int rbase16 = rowBase + s * 16;
    const int pc = (rbase16 + kBH) & (kN - 1);
    const bool hasPos = (pc >= colBase) && (pc < colBase + kColsPer);
#pragma unroll
    for (int j = 0; j < 4; ++j) {
      float sv = sacc[s][j];
      float pv = pacc[s][j];
#pragma unroll
      for (int m = 1; m < 16; m <<= 1) {
        sv += __shfl_xor(sv, m);
        pv += __shfl_xor(pv, m);
      }
      if (l15 == 0) {
        const int row = rbase16 + lhi * 4 + j;
        atomicAdd(&s_sum[row], sv);
        if (hasPos) atomicAdd(&pos_sum[row], pv);
      }
    }
  }
}

// ---------------- kernel 3: log, subtract pos, final reduce ---------------
__global__ void k_final(const float* __restrict__ s_sum,
                        const float* __restrict__ pos_sum,
                        float* __restrict__ out) {
  __shared__ float red[16];
  float acc = 0.0f;
  for (int r = threadIdx.x; r < kN; r += 1024)
    acc += logf(s_sum[r]) - pos_sum[r];
#pragma unroll
  for (int m = 1; m < 64; m <<= 1) acc += __shfl_xor(acc, m);
  const int wave = threadIdx.x >> 6;
  const int lane = threadIdx.x & 63;
  if (lane == 0) red[wave] = acc;
  __syncthreads();
  if (threadIdx.x == 0) {
    float t = 0.0f;
#pragma unroll
    for (int w = 0; w < 16; ++w) t += red[w];
    out[0] = t / (float)kN;
  }
}

extern "C" void kernel_launch(void* const* d_in, const int* in_sizes, int n_in,
                              void* d_out, int out_size, void* d_ws, size_t ws_size,
                              hipStream_t stream) {
  const float* e1 = (const float*)d_in[0];
  const float* e2 = (const float*)d_in[1];
  float* out = (float*)d_out;

  // ws layout: [Zn bf16 tiled: N*D*2 = 4MB][s_sum: N*4][pos_sum: N*4] ~4.07MB
  unsigned short* zn = (unsigned short*)d_ws;
  float* s_sum   = (float*)((char*)d_ws + (size_t)kN * kD * 2);
  float* pos_sum = s_sum + kN;

  hipLaunchKernelGGL(k_normalize, dim3(kN / 4), dim3(256), 0, stream,
                     e1, e2, zn, s_sum);
  hipLaunchKernelGGL(k_simlse, dim3(64 * kChunks), dim3(256), 0, stream,
                     zn, s_sum, pos_sum);
  hipLaunchKernelGGL(k_final, dim3(1), dim3(1024), 0, stream,
                     s_sum, pos_sum, out);
}

// Round 8
// 62.347 us; speedup vs baseline: 2.3365x; 1.0075x over previous
//
#include <hip/hip_runtime.h>
#include <hip/hip_bf16.h>

// NCE / NT-Xent loss, B=4096, D=256, temp=0.5.
// loss = mean_i( log(sum_{j!=i} exp(sim_ij)) - sim_{i,(i+B)%N} ), N=8192.
// |sim| <= 1/temp = 2 => exp(sim) <= e^2: no online max needed, plain sum(exp).
//
// Zn stored scaled by sqrt(2*log2(e)) so MFMA output is the exp2 argument.
// Fragment-tiled Zn layout: 16-row group g is an 8KB contiguous block;
// lane l's fragment ks of group g = contiguous 16B at zn + g*4096 + ks*512 + l*8.
//
// R8: L1-BW bound diagnosed (1.05 GB L1 traffic; occupancy/VGPR changes were
// no-ops). Fix: (a) 64 rows/wave (A=128 VGPR resident, arithmetic intensity
// 2x), (b) B tile staged once per block into double-buffered LDS via
// global_load_lds (linear dest, 8KB contiguous tile), m201-style counted
// vmcnt(2) + raw barriers, never draining to 0 in the main loop.

constexpr int kN  = 8192;        // 2B rows
constexpr int kD  = 256;         // embedding dim
constexpr int kBH = 4096;        // B
constexpr int kChunks  = 32;     // column chunks
constexpr int kColsPer = kN / kChunks;            // 256 cols per chunk
constexpr int kNT = kColsPer / 16;                // 16 B-tiles per chunk
constexpr float kSqrtScale = 1.6986436f;          // sqrt(2*log2(e))
constexpr float kLn2 = 0.6931471805599453f;       // acc -> sim/temp factor

typedef __attribute__((ext_vector_type(8))) short bf16x8;  // 8 bf16 = 4 VGPRs
typedef __attribute__((ext_vector_type(4))) float f32x4;

__device__ __forceinline__ unsigned short f2bf(float f) {
  union { float f; unsigned u; } x;
  x.f = f;
  unsigned u = x.u;
  return (unsigned short)((u + 0x7FFFu + ((u >> 16) & 1u)) >> 16);
}

__device__ __forceinline__ void gload_lds16(const short* g, short* l) {
  __builtin_amdgcn_global_load_lds(
      (const __attribute__((address_space(1))) void*)g,
      (__attribute__((address_space(3))) void*)l, 16, 0, 0);
}

// ---------------- kernel 1: row-normalize fp32 -> bf16 (tiled + scaled) ---
__global__ void k_normalize(const float* __restrict__ e1,
                            const float* __restrict__ e2,
                            unsigned short* __restrict__ zn,
                            float* __restrict__ accum /* 2*kN floats */) {
  if (blockIdx.x < 16) {
    float4 z4 = {0.f, 0.f, 0.f, 0.f};
    *reinterpret_cast<float4*>(accum + blockIdx.x * 1024 + threadIdx.x * 4) = z4;
  }
  const int wave = threadIdx.x >> 6;
  const int lane = threadIdx.x & 63;
  const int row  = blockIdx.x * 4 + wave;
  const float* src = (row < kBH) ? (e1 + (size_t)row * kD)
                                 : (e2 + (size_t)(row - kBH) * kD);
  float4 v = *reinterpret_cast<const float4*>(src + lane * 4);
  float ssq = v.x * v.x + v.y * v.y + v.z * v.z + v.w * v.w;
#pragma unroll
  for (int m = 1; m < 64; m <<= 1) ssq += __shfl_xor(ssq, m);
  const float invs = kSqrtScale / sqrtf(ssq);   // eps can never bind (|z|~16)
  ushort4 o;
  o.x = f2bf(v.x * invs);
  o.y = f2bf(v.y * invs);
  o.z = f2bf(v.z * invs);
  o.w = f2bf(v.w * invs);
  // lane holds dims 4*lane..4*lane+3 -> ks=lane>>3, lhi=(lane>>1)&3, dlo=(lane&1)*4
  const int g  = row >> 4;
  const int rr = row & 15;
  const size_t dst = (size_t)g * 4096 + (lane >> 3) * 512 +
                     ((lane >> 1) & 3) * 128 + rr * 8 + (lane & 1) * 4;
  *reinterpret_cast<ushort4*>(zn + dst) = o;
}

// ---------------- kernel 2: fused Z.Z^T + per-row sum(exp) ----------------
// Grid: 32 row-tiles (256 rows) x 32 col-chunks (256 cols) = 1024 blocks.
// Block: 4 waves; wave owns 64 rows as FOUR 16-row MFMA subtiles (A register-
// resident, 128 VGPR). B tiles (16 cols x 256 dims = 8KB contiguous in tiled
// layout) staged into double-buffered LDS via global_load_lds, shared by all
// 4 waves. Counted vmcnt(2): one tile always in flight, never drained to 0.
__global__ __launch_bounds__(256, 2)
void k_simlse(const unsigned short* __restrict__ zn,
              float* __restrict__ s_sum,
              float* __restrict__ pos_sum) {
  __shared__ __align__(16) short ldsB[2][4096];   // 2 x 8KB B tiles

  const int bid = blockIdx.x;
  const int rt  = bid >> 5;   // row tile 0..31 (256 rows each)
  const int ch  = bid & 31;   // column chunk 0..31
  const int wave = threadIdx.x >> 6;
  const int lane = threadIdx.x & 63;
  const int l15 = lane & 15;
  const int lhi = lane >> 4;
  const int rowBase = rt * 256 + wave * 64;
  const int colBase = ch * kColsPer;
  const int grpBase = colBase >> 4;     // first 16-col group of this chunk

  // Stage one 8KB B tile (group grpBase+tile) into ldsB[buf].
  // Each wave copies 2KB as 2 rounds of 64 lanes x 16B; linear dest.
  auto stage = [&](int buf, int tile) {
    const short* src = (const short*)zn + (size_t)(grpBase + tile) * 4096 +
                       wave * 1024;
    short* dst = &ldsB[buf][wave * 1024];
    gload_lds16(src + lane * 8, dst);
    gload_lds16(src + 512 + lane * 8, dst + 512);
  };

  // A fragments: 4 groups (64 rows), register-resident.
  bf16x8 a[4][8];
#pragma unroll
  for (int s = 0; s < 4; ++s) {
    const unsigned short* ap =
        zn + (size_t)((rowBase >> 4) + s) * 4096 + lane * 8;
#pragma unroll
    for (int ks = 0; ks < 8; ++ks)
      a[s][ks] = *reinterpret_cast<const bf16x8*>(ap + ks * 512);
  }

  float sacc[4][4];
  float pacc[4][4];
#pragma unroll
  for (int s = 0; s < 4; ++s)
#pragma unroll
    for (int j = 0; j < 4; ++j) { sacc[s][j] = 0.f; pacc[s][j] = 0.f; }

  stage(0, 0);   // prologue

#pragma unroll 1
  for (int t = 0; t < kNT; ++t) {
    stage((t + 1) & 1, (t + 1) & (kNT - 1));   // wrap-stage keeps loop uniform
    asm volatile("s_waitcnt vmcnt(2)" ::: "memory");  // cur tile's 2 loads done
    __builtin_amdgcn_s_barrier();

    // ds_read current tile fragments + MFMA (4 independent acc chains).
    const short* bt = &ldsB[t & 1][0];
    bf16x8 b[8];
#pragma unroll
    for (int ks = 0; ks < 8; ++ks)
      b[ks] = *reinterpret_cast<const bf16x8*>(bt + ks * 512 + lane * 8);

    f32x4 acc[4];
#pragma unroll
    for (int s = 0; s < 4; ++s) acc[s] = {0.f, 0.f, 0.f, 0.f};
#pragma unroll
    for (int ks = 0; ks < 8; ++ks) {
      const bf16x8 bk = b[ks];
#pragma unroll
      for (int s = 0; s < 4; ++s)
        acc[s] = __builtin_amdgcn_mfma_f32_16x16x32_bf16(a[s][ks], bk, acc[s], 0, 0, 0);
    }

    const int cb = colBase + t * 16;
    const int c  = cb + l15;   // this lane's column (C/D: col = lane&15)
#pragma unroll
    for (int s = 0; s < 4; ++s) {
      const int rbase16 = rowBase + s * 16;
      const bool diagT = (cb == rbase16);                       // wave-uniform
      const bool posT  = (cb == ((rbase16 + kBH) & (kN - 1)));  // wave-uniform
      if (!diagT && !posT) {
#pragma unroll
        for (int j = 0; j < 4; ++j)
          sacc[s][j] += exp2f(acc[s][j]);     // acc already = sim/temp*log2e
      } else {
#pragma unroll
        for (int j = 0; j < 4; ++j) {
          const int row = rbase16 + lhi * 4 + j;  // C/D: row=(lane>>4)*4+j
          const float v = acc[s][j] * kLn2;       // sim/temp
          float p = exp2f(acc[s][j]);
          if (diagT && c == row) p = 0.0f;                       // mask diag
          if (posT && c == ((row + kBH) & (kN - 1))) pacc[s][j] += v;
          sacc[s][j] += p;
        }
      }
    }

    __builtin_amdgcn_s_barrier();            // all reads of cur done before
    asm volatile("" ::: "memory");           // next stage overwrites it
  }

  // Fold across the 16-lane column group; lanes with l15==0 own rows.
#pragma unroll
  for (int s = 0; s < 4; ++s) {
    const int rbase16 = rowBase + s * 16;
    const int pc = (rbase16 + kBH) & (kN - 1);
    const bool hasPos = (pc >= colBase) && (pc < colBase + kColsPer);
#pragma unroll
    for (int j = 0; j < 4; ++j) {
      float sv = sacc[s][j];
      float pv = pacc[s][j];
#pragma unroll
      for (int m = 1; m < 16; m <<= 1) {
        sv += __shfl_xor(sv, m);
        pv += __shfl_xor(pv, m);
      }
      if (l15 == 0) {
        const int row = rbase16 + lhi * 4 + j;
        atomicAdd(&s_sum[row], sv);
        if (hasPos) atomicAdd(&pos_sum[row], pv);
      }
    }
  }
}

// ---------------- kernel 3: log, subtract pos, final reduce ---------------
__global__ void k_final(const float* __restrict__ s_sum,
                        const float* __restrict__ pos_sum,
                        float* __restrict__ out) {
  __shared__ float red[16];
  float acc = 0.0f;
  for (int r = threadIdx.x; r < kN; r += 1024)
    acc += logf(s_sum[r]) - pos_sum[r];
#pragma unroll
  for (int m = 1; m < 64; m <<= 1) acc += __shfl_xor(acc, m);
  const int wave = threadIdx.x >> 6;
  const int lane = threadIdx.x & 63;
  if (lane == 0) red[wave] = acc;
  __syncthreads();
  if (threadIdx.x == 0) {
    float t = 0.0f;
#pragma unroll
    for (int w = 0; w < 16; ++w) t += red[w];
    out[0] = t / (float)kN;
  }
}

extern "C" void kernel_launch(void* const* d_in, const int* in_sizes, int n_in,
                              void* d_out, int out_size, void* d_ws, size_t ws_size,
                              hipStream_t stream) {
  const float* e1 = (const float*)d_in[0];
  const float* e2 = (const float*)d_in[1];
  float* out = (float*)d_out;

  // ws layout: [Zn bf16 tiled: N*D*2 = 4MB][s_sum: N*4][pos_sum: N*4] ~4.07MB
  unsigned short* zn = (unsigned short*)d_ws;
  float* s_sum   = (float*)((char*)d_ws + (size_t)kN * kD * 2);
  float* pos_sum = s_sum + kN;

  hipLaunchKernelGGL(k_normalize, dim3(kN / 4), dim3(256), 0, stream,
                     e1, e2, zn, s_sum);
  hipLaunchKernelGGL(k_simlse, dim3(32 * kChunks), dim3(256), 0, stream,
                     zn, s_sum, pos_sum);
  hipLaunchKernelGGL(k_final, dim3(1), dim3(1024), 0, stream,
                     s_sum, pos_sum, out);
}